// Round 1
// baseline (1403.959 us; speedup 1.0000x reference)
//
#include <hip/hip_runtime.h>
#include <math.h>

// CoreAttention: B=2,S=2048,H=16,D=64  (fp32 in/out)
// scores = (q*8) @ k^T + bias ; masked -> 0.0 BEFORE softmax ; out = softmax(scores) @ v
// Round 1: pure fp32 VALU flash-attention baseline (correctness anchor).

constexpr int B  = 2;
constexpr int S  = 2048;
constexpr int H  = 16;
constexpr int D  = 64;
constexpr int QB = 64;    // q rows per workgroup
constexpr int KB = 64;    // k cols per tile
constexpr int LP = 65;    // LDS padded stride (stride-65: all accesses <=2-way bank alias)

__global__ __launch_bounds__(256, 2)
void core_attn_kernel(const float* __restrict__ qg,
                      const float* __restrict__ kg,
                      const float* __restrict__ vg,
                      const float* __restrict__ biasg,
                      const int*   __restrict__ maskg,
                      float* __restrict__ outg)
{
    __shared__ float Qs[QB * LP];
    __shared__ float Ks[KB * LP];
    __shared__ float Vs[KB * LP];
    __shared__ float Ss[QB * LP];      // scores, then P=exp(s-m) in place
    __shared__ float pmax[QB * 4];
    __shared__ float psum[QB * 4];
    __shared__ float row_m[QB];
    __shared__ float row_l[QB];
    __shared__ float s_alpha[QB];
    __shared__ float s_mnew[QB];

    const int t   = threadIdx.x;
    const int nqb = S / QB;                 // 32
    const int wg  = blockIdx.x;             // B*H*nqb = 1024
    const int b   = wg / (H * nqb);
    const int h   = (wg / nqb) % H;
    const int qb  = (wg % nqb) * QB;

    // ---- stage Q, scaled by 8 (source multiplies q by sqrt(D)) ----
    {
        const int r  = t >> 2;              // 0..63
        const int d0 = (t & 3) << 4;        // 0,16,32,48
        const float* src = qg + ((size_t)((b * S + qb + r) * H + h)) * D + d0;
        #pragma unroll
        for (int j = 0; j < 16; j += 4) {
            const float4 x = *(const float4*)(src + j);
            Qs[r * LP + d0 + j + 0] = x.x * 8.0f;
            Qs[r * LP + d0 + j + 1] = x.y * 8.0f;
            Qs[r * LP + d0 + j + 2] = x.z * 8.0f;
            Qs[r * LP + d0 + j + 3] = x.w * 8.0f;
        }
    }
    if (t < QB) { row_m[t] = -INFINITY; row_l[t] = 0.0f; }

    float O[4][4];
    #pragma unroll
    for (int i = 0; i < 4; ++i)
        #pragma unroll
        for (int j = 0; j < 4; ++j) O[i][j] = 0.0f;

    const int r0 = (t >> 4) << 2;   // score-block rows: 0..60
    const int c0 = (t & 15) << 2;   // score-block cols (and O d-cols): 0..60

    for (int kb0 = 0; kb0 < S; kb0 += KB) {
        __syncthreads();  // protects Ks/Vs/Ss from prev iter, covers Q-stage on iter 0

        // ---- stage K, V tiles ----
        {
            const int r  = t >> 2;
            const int d0 = (t & 3) << 4;
            const float* ks = kg + ((size_t)((b * S + kb0 + r) * H + h)) * D + d0;
            const float* vs = vg + ((size_t)((b * S + kb0 + r) * H + h)) * D + d0;
            #pragma unroll
            for (int j = 0; j < 16; j += 4) {
                const float4 x = *(const float4*)(ks + j);
                Ks[r * LP + d0 + j + 0] = x.x;
                Ks[r * LP + d0 + j + 1] = x.y;
                Ks[r * LP + d0 + j + 2] = x.z;
                Ks[r * LP + d0 + j + 3] = x.w;
                const float4 y = *(const float4*)(vs + j);
                Vs[r * LP + d0 + j + 0] = y.x;
                Vs[r * LP + d0 + j + 1] = y.y;
                Vs[r * LP + d0 + j + 2] = y.z;
                Vs[r * LP + d0 + j + 3] = y.w;
            }
        }
        __syncthreads();

        // ---- QK^T: 4x4 register block per thread ----
        float acc[4][4];
        #pragma unroll
        for (int i = 0; i < 4; ++i)
            #pragma unroll
            for (int j = 0; j < 4; ++j) acc[i][j] = 0.0f;

        #pragma unroll 4
        for (int d = 0; d < D; ++d) {
            float qv[4], kv[4];
            #pragma unroll
            for (int i = 0; i < 4; ++i) qv[i] = Qs[(r0 + i) * LP + d];
            #pragma unroll
            for (int j = 0; j < 4; ++j) kv[j] = Ks[(c0 + j) * LP + d];
            #pragma unroll
            for (int i = 0; i < 4; ++i)
                #pragma unroll
                for (int j = 0; j < 4; ++j)
                    acc[i][j] = fmaf(qv[i], kv[j], acc[i][j]);
        }

        // ---- + bias, mask -> 0.0, write scores to LDS ----
        #pragma unroll
        for (int i = 0; i < 4; ++i) {
            const int qrow = qb + r0 + i;
            const float4 b4 = *(const float4*)(biasg + ((size_t)((b * H + h) * S + qrow)) * S + kb0 + c0);
            const int4   m4 = *(const int4*)  (maskg + ((size_t)(b * S + qrow)) * S + kb0 + c0);
            Ss[(r0 + i) * LP + c0 + 0] = m4.x ? 0.0f : acc[i][0] + b4.x;
            Ss[(r0 + i) * LP + c0 + 1] = m4.y ? 0.0f : acc[i][1] + b4.y;
            Ss[(r0 + i) * LP + c0 + 2] = m4.z ? 0.0f : acc[i][2] + b4.z;
            Ss[(r0 + i) * LP + c0 + 3] = m4.w ? 0.0f : acc[i][3] + b4.w;
        }
        __syncthreads();

        // ---- tile max: 4 partials per row ----
        {
            const int r = t & 63, g = t >> 6;
            float m = -INFINITY;
            #pragma unroll
            for (int i = 0; i < 16; ++i) m = fmaxf(m, Ss[r * LP + g * 16 + i]);
            pmax[r * 4 + g] = m;
        }
        __syncthreads();

        if (t < QB) {
            const float m_old = row_m[t];
            const float tm = fmaxf(fmaxf(pmax[t * 4 + 0], pmax[t * 4 + 1]),
                                   fmaxf(pmax[t * 4 + 2], pmax[t * 4 + 3]));
            const float m_n = fmaxf(m_old, tm);
            s_mnew[t]  = m_n;
            s_alpha[t] = __expf(m_old - m_n);   // 0 on first tile (m_old=-inf)
            row_m[t]   = m_n;
        }
        __syncthreads();

        // ---- P = exp(s - m_new) in place, partial sums ----
        {
            const int r = t & 63, g = t >> 6;
            const float m_n = s_mnew[r];
            float sacc = 0.0f;
            #pragma unroll
            for (int i = 0; i < 16; ++i) {
                const float p = __expf(Ss[r * LP + g * 16 + i] - m_n);
                Ss[r * LP + g * 16 + i] = p;
                sacc += p;
            }
            psum[r * 4 + g] = sacc;
        }
        __syncthreads();

        if (t < QB)
            row_l[t] = row_l[t] * s_alpha[t] +
                       (psum[t * 4 + 0] + psum[t * 4 + 1] + psum[t * 4 + 2] + psum[t * 4 + 3]);

        // ---- PV: rescale O by alpha, accumulate P @ V ----
        {
            float a[4];
            #pragma unroll
            for (int i = 0; i < 4; ++i) a[i] = s_alpha[r0 + i];
            #pragma unroll
            for (int i = 0; i < 4; ++i)
                #pragma unroll
                for (int j = 0; j < 4; ++j) O[i][j] *= a[i];

            #pragma unroll 4
            for (int c = 0; c < KB; ++c) {
                float pv[4], vvv[4];
                #pragma unroll
                for (int i = 0; i < 4; ++i) pv[i] = Ss[(r0 + i) * LP + c];
                #pragma unroll
                for (int j = 0; j < 4; ++j) vvv[j] = Vs[c * LP + c0 + j];
                #pragma unroll
                for (int i = 0; i < 4; ++i)
                    #pragma unroll
                    for (int j = 0; j < 4; ++j)
                        O[i][j] = fmaf(pv[i], vvv[j], O[i][j]);
            }
        }
    }
    __syncthreads();  // row_l final values visible to all

    #pragma unroll
    for (int i = 0; i < 4; ++i) {
        const float inv = 1.0f / row_l[r0 + i];
        float4 o;
        o.x = O[i][0] * inv;
        o.y = O[i][1] * inv;
        o.z = O[i][2] * inv;
        o.w = O[i][3] * inv;
        *(float4*)(outg + ((size_t)((b * S + qb + r0 + i) * H + h)) * D + c0) = o;
    }
}

extern "C" void kernel_launch(void* const* d_in, const int* in_sizes, int n_in,
                              void* d_out, int out_size, void* d_ws, size_t ws_size,
                              hipStream_t stream) {
    const float* q    = (const float*)d_in[0];
    const float* k    = (const float*)d_in[1];
    const float* v    = (const float*)d_in[2];
    const float* bias = (const float*)d_in[3];
    const int*   mask = (const int*)d_in[4];   // jnp bool -> int32 per harness contract
    float* out = (float*)d_out;

    dim3 grid(B * H * (S / QB));   // 1024 workgroups
    dim3 block(256);
    hipLaunchKernelGGL(core_attn_kernel, grid, block, 0, stream,
                       q, k, v, bias, mask, out);
}